// Round 4
// baseline (855.124 us; speedup 1.0000x reference)
//
#include <hip/hip_runtime.h>
#include <hip/hip_bf16.h>

// GCN 2-layer. CSR build via 2-phase binning (write-dense), csr = 4B src records,
// w recomputed from isd in agg. Intermediates bf16. GEMM1 = bf16 MFMA.

#define NPB      128              // nodes per bucket (dst >> 7)
#define NBUCKET  782              // ceil(100000/128)
#define BCAP     3072             // bucket capacity (mean 2046, +23 sigma)

typedef __bf16 bf16x8 __attribute__((ext_vector_type(8)));
typedef float floatx4 __attribute__((ext_vector_type(4)));

__device__ inline unsigned short f2bf(float f) {      // RNE fp32->bf16
    unsigned u = __float_as_uint(f);
    u += 0x7FFF + ((u >> 16) & 1);
    return (unsigned short)(u >> 16);
}
__device__ inline float bflo(unsigned p) { return __uint_as_float(p << 16); }
__device__ inline float bfhi(unsigned p) { return __uint_as_float(p & 0xFFFF0000u); }

// ---------------- phase 1: bin edges + deg histogram (one edge pass) ----------------
__global__ __launch_bounds__(256) void k_bin(const int4* __restrict__ src4,
                                             const int4* __restrict__ dst4,
                                             int* __restrict__ deg,
                                             int* __restrict__ bcount,
                                             unsigned* __restrict__ buckets, int E4) {
    int t = blockIdx.x * blockDim.x + threadIdx.x;
    if (t >= E4) return;
    int4 s4 = src4[t];
    int4 d4 = dst4[t];
    int ss[4] = {s4.x, s4.y, s4.z, s4.w};
    int dd[4] = {d4.x, d4.y, d4.z, d4.w};
    #pragma unroll
    for (int j = 0; j < 4; ++j) {
        int d = dd[j];
        int b = d >> 7;
        int pos = atomicAdd(&bcount[b], 1);
        if (pos < BCAP)
            buckets[(size_t)b * BCAP + pos] = (unsigned)ss[j] | ((unsigned)(d & 127) << 17);
        atomicAdd(&deg[d], 1);
    }
}

// ---------------- isd + offsets (wave scan + 1 atomic/wave) ----------------
__global__ void k_isd_offsets(const int* __restrict__ deg, float* __restrict__ isd,
                              int* __restrict__ offsets, int* __restrict__ counter, int N) {
    int n = blockIdx.x * blockDim.x + threadIdx.x;
    int lane = threadIdx.x & 63;
    int d = (n < N) ? deg[n] : 0;
    if (n < N) isd[n] = (d > 0) ? rsqrtf((float)d) : 0.f;
    int pref = d;
    #pragma unroll
    for (int sh = 1; sh < 64; sh <<= 1) {
        int t = __shfl_up(pref, sh);
        if (lane >= sh) pref += t;
    }
    int total = __shfl(pref, 63);
    int base = 0;
    if (lane == 63) base = atomicAdd(counter, total);
    base = __shfl(base, 63);
    if (n < N) offsets[n] = base + pref - d;
}

// ---------------- phase 2: place within bucket via LDS cursors ----------------
__global__ __launch_bounds__(256) void k_place(const unsigned* __restrict__ buckets,
                                               const int* __restrict__ bcount,
                                               const int* __restrict__ offsets,
                                               int* __restrict__ csr, int N) {
    __shared__ int cur[NPB];
    int b = blockIdx.x;
    int node0 = b << 7;
    for (int i = threadIdx.x; i < NPB; i += 256) {
        int n = node0 + i;
        cur[i] = (n < N) ? offsets[n] : 0;
    }
    __syncthreads();
    int cnt = min(bcount[b], BCAP);
    const unsigned* bk = &buckets[(size_t)b * BCAP];
    for (int i = threadIdx.x; i < cnt; i += 256) {
        unsigned r = bk[i];
        int s = (int)(r & 0x1FFFFu);
        int dloc = (int)(r >> 17);
        int p = atomicAdd(&cur[dloc], 1);
        csr[p] = s;
    }
}

// ---------------- W1 -> bf16, MFMA B-fragment order ----------------
__global__ void k_prep_w1(const float* __restrict__ W1, unsigned short* __restrict__ w1s) {
    int flat = blockIdx.x * 256 + threadIdx.x;   // 0..4095
    int kt = flat >> 9;
    int nt = (flat >> 6) & 7;
    int lane = flat & 63;
    int kbase = kt * 32 + ((lane >> 4) << 3);
    int n = nt * 16 + (lane & 15);
    unsigned short v[8];
    #pragma unroll
    for (int j = 0; j < 8; ++j) v[j] = f2bf(W1[(size_t)(kbase + j) * 128 + n]);
    unsigned short* d = &w1s[(size_t)flat * 8];
    *(short4*)(d)     = make_short4(v[0], v[1], v[2], v[3]);
    *(short4*)(d + 4) = make_short4(v[4], v[5], v[6], v[7]);
}

// ---------------- GEMM1: h[N,128](bf16) = x[N,256] @ W1 , MFMA 16x16x32 ----------------
__global__ __launch_bounds__(256) void k_gemm1(const float* __restrict__ X,
                                               const unsigned short* __restrict__ w1s,
                                               unsigned short* __restrict__ H, int N) {
    __shared__ __align__(16) unsigned short smem[8192];
    unsigned short* sA = smem;
    unsigned short* sB = smem + 2048;
    int tid = threadIdx.x;
    int lane = tid & 63;
    int wave = tid >> 6;
    int wr = wave >> 1;
    int wc = wave & 1;
    int m0 = blockIdx.x * 64;

    floatx4 acc[2][4] = {};

    for (int kt = 0; kt < 8; ++kt) {
        #pragma unroll
        for (int i = 0; i < 2; ++i) {
            int f = tid * 2 + i;
            int row = f >> 3;
            int c4 = (f & 7) * 4;
            float4 v = make_float4(0.f, 0.f, 0.f, 0.f);
            int grow = m0 + row;
            if (grow < N) v = *(const float4*)&X[(size_t)grow * 256 + kt * 32 + c4];
            int mt = row >> 4;
            int flane = (row & 15) | ((c4 >> 3) << 4);
            int j0 = c4 & 7;
            unsigned short* d = &sA[(size_t)(mt * 64 + flane) * 8 + j0];
            *(short4*)d = make_short4(f2bf(v.x), f2bf(v.y), f2bf(v.z), f2bf(v.w));
        }
        {
            const float4* srcp = (const float4*)&w1s[(size_t)kt * 4096];
            float4* dstp = (float4*)sB;
            dstp[tid] = srcp[tid];
            dstp[tid + 256] = srcp[tid + 256];
        }
        __syncthreads();
        bf16x8 a[2], b[4];
        #pragma unroll
        for (int p = 0; p < 2; ++p)
            a[p] = *(const bf16x8*)&sA[(size_t)((wr * 2 + p) * 64 + lane) * 8];
        #pragma unroll
        for (int q = 0; q < 4; ++q)
            b[q] = *(const bf16x8*)&sB[(size_t)((wc * 4 + q) * 64 + lane) * 8];
        #pragma unroll
        for (int p = 0; p < 2; ++p)
            #pragma unroll
            for (int q = 0; q < 4; ++q)
                acc[p][q] = __builtin_amdgcn_mfma_f32_16x16x32_bf16(a[p], b[q], acc[p][q], 0, 0, 0);
        __syncthreads();
    }
    #pragma unroll
    for (int p = 0; p < 2; ++p)
        #pragma unroll
        for (int q = 0; q < 4; ++q)
            #pragma unroll
            for (int r = 0; r < 4; ++r) {
                int rl = wr * 32 + p * 16 + ((lane >> 4) << 2) + r;
                int c = wc * 64 + q * 16 + (lane & 15);
                smem[rl * 128 + c] = f2bf(acc[p][q][r]);
            }
    __syncthreads();
    #pragma unroll
    for (int i = 0; i < 4; ++i) {
        int f = tid + i * 256;
        int row = f >> 4;
        int c8 = (f & 15) * 8;
        int grow = m0 + row;
        if (grow < N)
            *(float4*)&H[(size_t)grow * 128 + c8] = *(const float4*)&smem[row * 128 + c8];
    }
}

// ---------------- agg1: h1(bf16) = relu(b1 + sum isd[s]*isd[n]*h[src]) , C=128 -------
// wave/node; node scalar => csr+isd reads are s_loads; 16 gathers in flight, predicated
__global__ __launch_bounds__(256) void k_agg1(const unsigned* __restrict__ Hu,
                                              const int* __restrict__ csr,
                                              const float* __restrict__ isd,
                                              const int* __restrict__ offsets,
                                              const int* __restrict__ deg,
                                              const float* __restrict__ b1,
                                              unsigned* __restrict__ H1u, int N) {
    int node = __builtin_amdgcn_readfirstlane((blockIdx.x * blockDim.x + threadIdx.x) >> 6);
    int lane = threadIdx.x & 63;
    if (node >= N) return;
    int start = offsets[node];
    int cnt = deg[node];
    float isdn = isd[node];
    float acc0 = 0.f, acc1 = 0.f;
    for (int i = 0; i < cnt; i += 16) {
        int s[16];
        float f[16];
        #pragma unroll
        for (int j = 0; j < 16; ++j) {
            // over-read is clamped (csr has tail slack); invalid lanes get w=0
            unsigned raw = (unsigned)csr[start + i + j];
            s[j] = (int)min(raw, (unsigned)(N - 1));
            f[j] = isd[s[j]];
        }
        unsigned p[16];
        #pragma unroll
        for (int j = 0; j < 16; ++j) p[j] = Hu[(size_t)s[j] * 64 + lane];
        #pragma unroll
        for (int j = 0; j < 16; ++j) {
            float w = (i + j < cnt) ? f[j] * isdn : 0.f;
            acc0 = fmaf(w, bflo(p[j]), acc0);
            acc1 = fmaf(w, bfhi(p[j]), acc1);
        }
    }
    float r0 = fmaxf(acc0 + b1[2 * lane], 0.f);
    float r1 = fmaxf(acc1 + b1[2 * lane + 1], 0.f);
    H1u[(size_t)node * 64 + lane] = (unsigned)f2bf(r0) | ((unsigned)f2bf(r1) << 16);
}

// ---------------- GEMM2: h2[N,40](bf16) = h1(bf16) @ W2[128,40] ----------------
__global__ __launch_bounds__(256) void k_gemm2(const unsigned short* __restrict__ H1,
                                               const float* __restrict__ W2,
                                               unsigned short* __restrict__ H2, int N) {
    __shared__ float sH[64][132];
    __shared__ float sW[128 * 40];
    int tid = threadIdx.x;
    int block_row = blockIdx.x * 64;
    for (int i = tid; i < 64 * 16; i += 256) {
        int r = i >> 4;
        int c8 = (i & 15) * 8;
        int grow = block_row + r;
        uint4 v = make_uint4(0, 0, 0, 0);
        if (grow < N) v = *(const uint4*)&H1[(size_t)grow * 128 + c8];
        float* d = &sH[r][c8];
        d[0] = bflo(v.x); d[1] = bfhi(v.x);
        d[2] = bflo(v.y); d[3] = bfhi(v.y);
        d[4] = bflo(v.z); d[5] = bfhi(v.z);
        d[6] = bflo(v.w); d[7] = bfhi(v.w);
    }
    for (int i = tid; i < 1280; i += 256)
        *(float4*)&sW[i * 4] = *(const float4*)&W2[(size_t)i * 4];
    __syncthreads();

    int row = tid >> 2;
    int c0 = (tid & 3) * 10;
    float acc[10] = {};
    for (int k = 0; k < 128; ++k) {
        float hv = sH[row][k];
        #pragma unroll
        for (int j = 0; j < 5; ++j) {
            float2 wv = *(const float2*)&sW[k * 40 + c0 + 2 * j];
            acc[2 * j]     = fmaf(hv, wv.x, acc[2 * j]);
            acc[2 * j + 1] = fmaf(hv, wv.y, acc[2 * j + 1]);
        }
    }
    int grow = block_row + row;
    if (grow < N) {
        unsigned* o = (unsigned*)&H2[(size_t)grow * 40 + c0];
        #pragma unroll
        for (int j = 0; j < 5; ++j)
            o[j] = (unsigned)f2bf(acc[2 * j]) | ((unsigned)f2bf(acc[2 * j + 1]) << 16);
    }
}

// ---------------- agg2: out[n][c](fp32) = b2 + sum w*h2[src] , C=40 ----------------
// lane = 20*g + c : 3 edge-groups in parallel, cross-group shfl reduce at end
__global__ __launch_bounds__(256) void k_agg2(const unsigned* __restrict__ Hu,
                                              const int* __restrict__ csr,
                                              const float* __restrict__ isd,
                                              const int* __restrict__ offsets,
                                              const int* __restrict__ deg,
                                              const float* __restrict__ b2,
                                              float* __restrict__ out, int N) {
    int node = __builtin_amdgcn_readfirstlane((blockIdx.x * blockDim.x + threadIdx.x) >> 6);
    int lane = threadIdx.x & 63;
    if (node >= N) return;
    int start = offsets[node];
    int cnt = deg[node];
    float isdn = isd[node];
    int g = lane / 20;         // 0..3 (g==3 idle)
    int c = lane % 20;
    bool active = g < 3;
    float acc0 = 0.f, acc1 = 0.f;
    for (int i0 = 0; i0 < cnt; i0 += 12) {
        #pragma unroll
        for (int j = 0; j < 4; ++j) {
            int e = i0 + j * 3 + g;
            if (active && e < cnt) {
                int s = csr[start + e];
                unsigned p = Hu[(size_t)s * 20 + c];
                float w = isd[s] * isdn;
                acc0 = fmaf(w, bflo(p), acc0);
                acc1 = fmaf(w, bfhi(p), acc1);
            }
        }
    }
    float t0 = __shfl(acc0, (lane + 20) & 63) + __shfl(acc0, (lane + 40) & 63);
    float t1 = __shfl(acc1, (lane + 20) & 63) + __shfl(acc1, (lane + 40) & 63);
    acc0 += t0;
    acc1 += t1;
    if (lane < 20)
        *(float2*)&out[(size_t)node * 40 + 2 * lane] =
            make_float2(acc0 + b2[2 * lane], acc1 + b2[2 * lane + 1]);
}

extern "C" void kernel_launch(void* const* d_in, const int* in_sizes, int n_in,
                              void* d_out, int out_size, void* d_ws, size_t ws_size,
                              hipStream_t stream) {
    const float* x  = (const float*)d_in[0];
    const int*  src = (const int*)d_in[1];
    const int*  dst = (const int*)d_in[2];
    const float* W1 = (const float*)d_in[3];
    const float* b1 = (const float*)d_in[4];
    const float* W2 = (const float*)d_in[5];
    const float* b2 = (const float*)d_in[6];
    float* out = (float*)d_out;

    const int N = in_sizes[0] / 256;   // 100000
    const int E = in_sizes[1];         // 1600000

    char* w = (char*)d_ws;
    auto alloc = [&](size_t bytes) -> void* {
        void* p = (void*)w;
        w += (bytes + 15) & ~(size_t)15;
        return p;
    };
    int*      deg     = (int*)alloc((size_t)N * 4);         // zeroed below
    int*      bcount  = (int*)alloc((size_t)NBUCKET * 4);   // zeroed below
    int*      counter = (int*)alloc(16);                    // zeroed below
    float*    isd     = (float*)alloc((size_t)N * 4);
    int*      offsets = (int*)alloc((size_t)N * 4);
    unsigned* buckets = (unsigned*)alloc((size_t)NBUCKET * BCAP * 4);
    int*      csr     = (int*)alloc((size_t)E * 4 + 64);    // +16 ints tail slack
    unsigned short* w1s = (unsigned short*)alloc(32768 * 2);
    unsigned short* h   = (unsigned short*)alloc((size_t)N * 128 * 2);
    unsigned short* h1  = (unsigned short*)alloc((size_t)N * 128 * 2);
    unsigned short* h2  = h;   // h dead after agg1

    // deg, bcount, counter are contiguous 16B-rounded regions
    size_t z = (((size_t)N * 4 + 15) & ~15ull) + (((size_t)NBUCKET * 4 + 15) & ~15ull) + 16;
    hipMemsetAsync(deg, 0, z, stream);

    int E4 = E / 4;
    k_bin<<<(E4 + 255) / 256, 256, 0, stream>>>((const int4*)src, (const int4*)dst,
                                                deg, bcount, buckets, E4);
    k_isd_offsets<<<(N + 255) / 256, 256, 0, stream>>>(deg, isd, offsets, counter, N);
    k_place<<<NBUCKET, 256, 0, stream>>>(buckets, bcount, offsets, csr, N);
    k_prep_w1<<<16, 256, 0, stream>>>(W1, w1s);
    k_gemm1<<<(N + 63) / 64, 256, 0, stream>>>(x, w1s, h, N);
    k_agg1<<<(N + 3) / 4, 256, 0, stream>>>((const unsigned*)h, csr, isd, offsets, deg,
                                            b1, (unsigned*)h1, N);
    k_gemm2<<<(N + 63) / 64, 256, 0, stream>>>(h1, W2, h2, N);
    k_agg2<<<(N + 3) / 4, 256, 0, stream>>>((const unsigned*)h2, csr, isd, offsets, deg,
                                            b2, out, N);
}

// Round 5
// 465.389 us; speedup vs baseline: 1.8374x; 1.8374x over previous
//
#include <hip/hip_runtime.h>
#include <hip/hip_bf16.h>

// GCN 2-layer. CSR build via block-local radix partition (dense writes, no per-edge
// global atomics) -> per-bucket deg count -> per-bucket placement. csr = 4B src,
// w recomputed from isd. Intermediates bf16. GEMM1 = bf16 MFMA.

#define CHUNK   8192              // edges per partition block
#define NPB     1024              // nodes per bucket (dst >> 10)
#define NBUCK   98                // ceil(100000/1024)
#define BBCAP   20480             // bucket capacity (mean 16384, +32 sigma)

typedef __bf16 bf16x8 __attribute__((ext_vector_type(8)));
typedef float floatx4 __attribute__((ext_vector_type(4)));

__device__ inline unsigned short f2bf(float f) {      // RNE fp32->bf16
    unsigned u = __float_as_uint(f);
    u += 0x7FFF + ((u >> 16) & 1);
    return (unsigned short)(u >> 16);
}
__device__ inline float bflo(unsigned p) { return __uint_as_float(p << 16); }
__device__ inline float bfhi(unsigned p) { return __uint_as_float(p & 0xFFFF0000u); }

// ---------------- pass 1: block-local radix partition by dst>>10 ----------------
// rec = src (17b) | (dst&1023)<<17
__global__ __launch_bounds__(256) void k_part(const int* __restrict__ src,
                                              const int* __restrict__ dst,
                                              int* __restrict__ gcursor,
                                              unsigned* __restrict__ buckets, int E) {
    __shared__ unsigned srec[CHUNK];          // 32 KB
    __shared__ unsigned char sb8[CHUNK];      // 8 KB
    __shared__ int hist[NBUCK];
    __shared__ int lbase[NBUCK];
    __shared__ int gbase[NBUCK];
    __shared__ int scanbuf[128];
    int t = threadIdx.x;
    int base = blockIdx.x * CHUNK;
    int cnt = min(CHUNK, E - base);           // multiple of 4 (E%4==0, base%4==0)
    for (int i = t; i < NBUCK; i += 256) hist[i] = 0;
    __syncthreads();

    unsigned rec[32];
    unsigned br[32];                          // b (7b) | rank<<7
    bool valid[8];
    #pragma unroll
    for (int k = 0; k < 8; ++k) {
        int e0 = k * 1024 + t * 4;
        valid[k] = (e0 < cnt);
        if (valid[k]) {
            int4 s4 = *(const int4*)&src[base + e0];
            int4 d4 = *(const int4*)&dst[base + e0];
            int ss[4] = {s4.x, s4.y, s4.z, s4.w};
            int dd[4] = {d4.x, d4.y, d4.z, d4.w};
            #pragma unroll
            for (int j = 0; j < 4; ++j) {
                int b = dd[j] >> 10;
                int r = atomicAdd(&hist[b], 1);           // LDS atomic
                rec[k * 4 + j] = (unsigned)ss[j] | ((unsigned)(dd[j] & 1023) << 17);
                br[k * 4 + j] = (unsigned)b | ((unsigned)r << 7);
            }
        }
    }
    __syncthreads();
    // inclusive Hillis-Steele scan over 98 (padded 128) entries
    if (t < 128) scanbuf[t] = (t < NBUCK) ? hist[t] : 0;
    __syncthreads();
    for (int s = 1; s < 128; s <<= 1) {
        int v = 0;
        if (t < 128 && t >= s) v = scanbuf[t - s];
        __syncthreads();
        if (t < 128) scanbuf[t] += v;
        __syncthreads();
    }
    if (t < NBUCK) {
        lbase[t] = scanbuf[t] - hist[t];                  // exclusive base
        gbase[t] = atomicAdd(&gcursor[t], hist[t]);       // 98 global atomics/block
    }
    __syncthreads();
    // reorder into LDS, grouped by bucket
    #pragma unroll
    for (int k = 0; k < 8; ++k) {
        if (valid[k]) {
            #pragma unroll
            for (int j = 0; j < 4; ++j) {
                unsigned b = br[k * 4 + j] & 127u;
                unsigned r = br[k * 4 + j] >> 7;
                int p = lbase[b] + (int)r;
                srec[p] = rec[k * 4 + j];
                sb8[p] = (unsigned char)b;
            }
        }
    }
    __syncthreads();
    // dense flat write: consecutive i -> consecutive addresses within each run
    for (int i = t; i < cnt; i += 256) {
        int b = sb8[i];
        int pos = gbase[b] + (i - lbase[b]);
        if (pos < BBCAP) buckets[(size_t)b * BBCAP + pos] = srec[i];
    }
}

// ---------------- pass 2a: per-bucket deg histogram (dense) ----------------
__global__ __launch_bounds__(256) void k_count(const unsigned* __restrict__ buckets,
                                               const int* __restrict__ gcursor,
                                               int* __restrict__ deg, int N) {
    __shared__ int hist[NPB];
    int b = blockIdx.x;
    for (int i = threadIdx.x; i < NPB; i += 256) hist[i] = 0;
    __syncthreads();
    int cnt = min(gcursor[b], BBCAP);
    const unsigned* bk = &buckets[(size_t)b * BBCAP];
    for (int i = threadIdx.x; i < cnt; i += 256)
        atomicAdd(&hist[bk[i] >> 17], 1);
    __syncthreads();
    int node0 = b << 10;
    for (int i = threadIdx.x; i < NPB; i += 256)
        if (node0 + i < N) deg[node0 + i] = hist[i];
}

// ---------------- isd + offsets (wave scan + 1 atomic/wave) ----------------
__global__ void k_isd_offsets(const int* __restrict__ deg, float* __restrict__ isd,
                              int* __restrict__ offsets, int* __restrict__ counter, int N) {
    int n = blockIdx.x * blockDim.x + threadIdx.x;
    int lane = threadIdx.x & 63;
    int d = (n < N) ? deg[n] : 0;
    if (n < N) isd[n] = (d > 0) ? rsqrtf((float)d) : 0.f;
    int pref = d;
    #pragma unroll
    for (int sh = 1; sh < 64; sh <<= 1) {
        int t = __shfl_up(pref, sh);
        if (lane >= sh) pref += t;
    }
    int total = __shfl(pref, 63);
    int base = 0;
    if (lane == 63) base = atomicAdd(counter, total);
    base = __shfl(base, 63);
    if (n < N) offsets[n] = base + pref - d;
}

// ---------------- pass 2b: placement via LDS cursors (dense 64KB window) --------
__global__ __launch_bounds__(256) void k_place(const unsigned* __restrict__ buckets,
                                               const int* __restrict__ gcursor,
                                               const int* __restrict__ offsets,
                                               int* __restrict__ csr, int N) {
    __shared__ int cur[NPB];
    int b = blockIdx.x;
    int node0 = b << 10;
    for (int i = threadIdx.x; i < NPB; i += 256)
        cur[i] = (node0 + i < N) ? offsets[node0 + i] : 0;
    __syncthreads();
    int cnt = min(gcursor[b], BBCAP);
    const unsigned* bk = &buckets[(size_t)b * BBCAP];
    for (int i = threadIdx.x; i < cnt; i += 256) {
        unsigned r = bk[i];
        int p = atomicAdd(&cur[r >> 17], 1);
        csr[p] = (int)(r & 0x1FFFFu);
    }
}

// ---------------- W1 -> bf16, MFMA B-fragment order ----------------
__global__ void k_prep_w1(const float* __restrict__ W1, unsigned short* __restrict__ w1s) {
    int flat = blockIdx.x * 256 + threadIdx.x;   // 0..4095
    int kt = flat >> 9;
    int nt = (flat >> 6) & 7;
    int lane = flat & 63;
    int kbase = kt * 32 + ((lane >> 4) << 3);
    int n = nt * 16 + (lane & 15);
    unsigned short v[8];
    #pragma unroll
    for (int j = 0; j < 8; ++j) v[j] = f2bf(W1[(size_t)(kbase + j) * 128 + n]);
    unsigned short* d = &w1s[(size_t)flat * 8];
    *(short4*)(d)     = make_short4(v[0], v[1], v[2], v[3]);
    *(short4*)(d + 4) = make_short4(v[4], v[5], v[6], v[7]);
}

// ---------------- GEMM1: h[N,128](bf16) = x[N,256] @ W1 , MFMA 16x16x32 ----------------
__global__ __launch_bounds__(256) void k_gemm1(const float* __restrict__ X,
                                               const unsigned short* __restrict__ w1s,
                                               unsigned short* __restrict__ H, int N) {
    __shared__ __align__(16) unsigned short smem[8192];
    unsigned short* sA = smem;
    unsigned short* sB = smem + 2048;
    int tid = threadIdx.x;
    int lane = tid & 63;
    int wave = tid >> 6;
    int wr = wave >> 1;
    int wc = wave & 1;
    int m0 = blockIdx.x * 64;

    floatx4 acc[2][4] = {};

    for (int kt = 0; kt < 8; ++kt) {
        #pragma unroll
        for (int i = 0; i < 2; ++i) {
            int f = tid * 2 + i;
            int row = f >> 3;
            int c4 = (f & 7) * 4;
            float4 v = make_float4(0.f, 0.f, 0.f, 0.f);
            int grow = m0 + row;
            if (grow < N) v = *(const float4*)&X[(size_t)grow * 256 + kt * 32 + c4];
            int mt = row >> 4;
            int flane = (row & 15) | ((c4 >> 3) << 4);
            int j0 = c4 & 7;
            unsigned short* d = &sA[(size_t)(mt * 64 + flane) * 8 + j0];
            *(short4*)d = make_short4(f2bf(v.x), f2bf(v.y), f2bf(v.z), f2bf(v.w));
        }
        {
            const float4* srcp = (const float4*)&w1s[(size_t)kt * 4096];
            float4* dstp = (float4*)sB;
            dstp[tid] = srcp[tid];
            dstp[tid + 256] = srcp[tid + 256];
        }
        __syncthreads();
        bf16x8 a[2], b[4];
        #pragma unroll
        for (int p = 0; p < 2; ++p)
            a[p] = *(const bf16x8*)&sA[(size_t)((wr * 2 + p) * 64 + lane) * 8];
        #pragma unroll
        for (int q = 0; q < 4; ++q)
            b[q] = *(const bf16x8*)&sB[(size_t)((wc * 4 + q) * 64 + lane) * 8];
        #pragma unroll
        for (int p = 0; p < 2; ++p)
            #pragma unroll
            for (int q = 0; q < 4; ++q)
                acc[p][q] = __builtin_amdgcn_mfma_f32_16x16x32_bf16(a[p], b[q], acc[p][q], 0, 0, 0);
        __syncthreads();
    }
    #pragma unroll
    for (int p = 0; p < 2; ++p)
        #pragma unroll
        for (int q = 0; q < 4; ++q)
            #pragma unroll
            for (int r = 0; r < 4; ++r) {
                int rl = wr * 32 + p * 16 + ((lane >> 4) << 2) + r;
                int c = wc * 64 + q * 16 + (lane & 15);
                smem[rl * 128 + c] = f2bf(acc[p][q][r]);
            }
    __syncthreads();
    #pragma unroll
    for (int i = 0; i < 4; ++i) {
        int f = tid + i * 256;
        int row = f >> 4;
        int c8 = (f & 15) * 8;
        int grow = m0 + row;
        if (grow < N)
            *(float4*)&H[(size_t)grow * 128 + c8] = *(const float4*)&smem[row * 128 + c8];
    }
}

// ---------------- agg1: h1(bf16) = relu(b1 + sum isd[s]*isd[n]*h[src]) , C=128 -------
__global__ __launch_bounds__(256) void k_agg1(const unsigned* __restrict__ Hu,
                                              const int* __restrict__ csr,
                                              const float* __restrict__ isd,
                                              const int* __restrict__ offsets,
                                              const int* __restrict__ deg,
                                              const float* __restrict__ b1,
                                              unsigned* __restrict__ H1u, int N) {
    int node = __builtin_amdgcn_readfirstlane((blockIdx.x * blockDim.x + threadIdx.x) >> 6);
    int lane = threadIdx.x & 63;
    if (node >= N) return;
    int start = offsets[node];
    int cnt = deg[node];
    float isdn = isd[node];
    float acc0 = 0.f, acc1 = 0.f;
    for (int i = 0; i < cnt; i += 16) {
        int s[16];
        float f[16];
        #pragma unroll
        for (int j = 0; j < 16; ++j) {
            unsigned raw = (unsigned)csr[start + i + j];   // tail slack in csr
            s[j] = (int)min(raw, (unsigned)(N - 1));
            f[j] = isd[s[j]];
        }
        unsigned p[16];
        #pragma unroll
        for (int j = 0; j < 16; ++j) p[j] = Hu[(size_t)s[j] * 64 + lane];
        #pragma unroll
        for (int j = 0; j < 16; ++j) {
            float w = (i + j < cnt) ? f[j] * isdn : 0.f;
            acc0 = fmaf(w, bflo(p[j]), acc0);
            acc1 = fmaf(w, bfhi(p[j]), acc1);
        }
    }
    float r0 = fmaxf(acc0 + b1[2 * lane], 0.f);
    float r1 = fmaxf(acc1 + b1[2 * lane + 1], 0.f);
    H1u[(size_t)node * 64 + lane] = (unsigned)f2bf(r0) | ((unsigned)f2bf(r1) << 16);
}

// ---------------- GEMM2: h2[N,40](bf16) = h1(bf16) @ W2[128,40] ----------------
__global__ __launch_bounds__(256) void k_gemm2(const unsigned short* __restrict__ H1,
                                               const float* __restrict__ W2,
                                               unsigned short* __restrict__ H2, int N) {
    __shared__ float sH[64][132];
    __shared__ float sW[128 * 40];
    int tid = threadIdx.x;
    int block_row = blockIdx.x * 64;
    for (int i = tid; i < 64 * 16; i += 256) {
        int r = i >> 4;
        int c8 = (i & 15) * 8;
        int grow = block_row + r;
        uint4 v = make_uint4(0, 0, 0, 0);
        if (grow < N) v = *(const uint4*)&H1[(size_t)grow * 128 + c8];
        float* d = &sH[r][c8];
        d[0] = bflo(v.x); d[1] = bfhi(v.x);
        d[2] = bflo(v.y); d[3] = bfhi(v.y);
        d[4] = bflo(v.z); d[5] = bfhi(v.z);
        d[6] = bflo(v.w); d[7] = bfhi(v.w);
    }
    for (int i = tid; i < 1280; i += 256)
        *(float4*)&sW[i * 4] = *(const float4*)&W2[(size_t)i * 4];
    __syncthreads();

    int row = tid >> 2;
    int c0 = (tid & 3) * 10;
    float acc[10] = {};
    for (int k = 0; k < 128; ++k) {
        float hv = sH[row][k];
        #pragma unroll
        for (int j = 0; j < 5; ++j) {
            float2 wv = *(const float2*)&sW[k * 40 + c0 + 2 * j];
            acc[2 * j]     = fmaf(hv, wv.x, acc[2 * j]);
            acc[2 * j + 1] = fmaf(hv, wv.y, acc[2 * j + 1]);
        }
    }
    int grow = block_row + row;
    if (grow < N) {
        unsigned* o = (unsigned*)&H2[(size_t)grow * 40 + c0];
        #pragma unroll
        for (int j = 0; j < 5; ++j)
            o[j] = (unsigned)f2bf(acc[2 * j]) | ((unsigned)f2bf(acc[2 * j + 1]) << 16);
    }
}

// ---------------- agg2: out[n][c](fp32) = b2 + sum w*h2[src] , C=40 ----------------
__global__ __launch_bounds__(256) void k_agg2(const unsigned* __restrict__ Hu,
                                              const int* __restrict__ csr,
                                              const float* __restrict__ isd,
                                              const int* __restrict__ offsets,
                                              const int* __restrict__ deg,
                                              const float* __restrict__ b2,
                                              float* __restrict__ out, int N) {
    int node = __builtin_amdgcn_readfirstlane((blockIdx.x * blockDim.x + threadIdx.x) >> 6);
    int lane = threadIdx.x & 63;
    if (node >= N) return;
    int start = offsets[node];
    int cnt = deg[node];
    float isdn = isd[node];
    int g = lane / 20;         // 0..3 (g==3 idle)
    int c = lane % 20;
    bool active = g < 3;
    float acc0 = 0.f, acc1 = 0.f;
    for (int i0 = 0; i0 < cnt; i0 += 12) {
        #pragma unroll
        for (int j = 0; j < 4; ++j) {
            int e = i0 + j * 3 + g;
            if (active && e < cnt) {
                int s = csr[start + e];
                unsigned p = Hu[(size_t)s * 20 + c];
                float w = isd[s] * isdn;
                acc0 = fmaf(w, bflo(p), acc0);
                acc1 = fmaf(w, bfhi(p), acc1);
            }
        }
    }
    float t0 = __shfl(acc0, (lane + 20) & 63) + __shfl(acc0, (lane + 40) & 63);
    float t1 = __shfl(acc1, (lane + 20) & 63) + __shfl(acc1, (lane + 40) & 63);
    acc0 += t0;
    acc1 += t1;
    if (lane < 20)
        *(float2*)&out[(size_t)node * 40 + 2 * lane] =
            make_float2(acc0 + b2[2 * lane], acc1 + b2[2 * lane + 1]);
}

extern "C" void kernel_launch(void* const* d_in, const int* in_sizes, int n_in,
                              void* d_out, int out_size, void* d_ws, size_t ws_size,
                              hipStream_t stream) {
    const float* x  = (const float*)d_in[0];
    const int*  src = (const int*)d_in[1];
    const int*  dst = (const int*)d_in[2];
    const float* W1 = (const float*)d_in[3];
    const float* b1 = (const float*)d_in[4];
    const float* W2 = (const float*)d_in[5];
    const float* b2 = (const float*)d_in[6];
    float* out = (float*)d_out;

    const int N = in_sizes[0] / 256;   // 100000
    const int E = in_sizes[1];         // 1600000

    char* w = (char*)d_ws;
    auto alloc = [&](size_t bytes) -> void* {
        void* p = (void*)w;
        w += (bytes + 15) & ~(size_t)15;
        return p;
    };
    int*      gcursor = (int*)alloc(128 * 4);               // zeroed (NBUCK=98 used)
    int*      counter = (int*)alloc(16);                    // zeroed
    int*      deg     = (int*)alloc((size_t)N * 4);         // fully written by k_count
    float*    isd     = (float*)alloc((size_t)N * 4);
    int*      offsets = (int*)alloc((size_t)N * 4);
    unsigned* buckets = (unsigned*)alloc((size_t)NBUCK * BBCAP * 4);
    int*      csr     = (int*)alloc((size_t)E * 4 + 64);    // +16 ints tail slack
    unsigned short* w1s = (unsigned short*)alloc(32768 * 2);
    unsigned short* h   = (unsigned short*)alloc((size_t)N * 128 * 2);
    unsigned short* h1  = (unsigned short*)alloc((size_t)N * 128 * 2);
    unsigned short* h2  = h;   // h dead after agg1

    hipMemsetAsync(gcursor, 0, 128 * 4 + 16, stream);

    int nchunk = (E + CHUNK - 1) / CHUNK;   // 196
    k_part<<<nchunk, 256, 0, stream>>>(src, dst, gcursor, buckets, E);
    k_count<<<NBUCK, 256, 0, stream>>>(buckets, gcursor, deg, N);
    k_isd_offsets<<<(N + 255) / 256, 256, 0, stream>>>(deg, isd, offsets, counter, N);
    k_place<<<NBUCK, 256, 0, stream>>>(buckets, gcursor, offsets, csr, N);
    k_prep_w1<<<16, 256, 0, stream>>>(W1, w1s);
    k_gemm1<<<(N + 63) / 64, 256, 0, stream>>>(x, w1s, h, N);
    k_agg1<<<(N + 3) / 4, 256, 0, stream>>>((const unsigned*)h, csr, isd, offsets, deg,
                                            b1, (unsigned*)h1, N);
    k_gemm2<<<(N + 63) / 64, 256, 0, stream>>>(h1, W2, h2, N);
    k_agg2<<<(N + 3) / 4, 256, 0, stream>>>((const unsigned*)h2, csr, isd, offsets, deg,
                                            b2, out, N);
}

// Round 6
// 442.646 us; speedup vs baseline: 1.9318x; 1.0514x over previous
//
#include <hip/hip_runtime.h>
#include <hip/hip_bf16.h>

// GCN 2-layer. CSR build via block-local radix partition (dense writes, no per-edge
// global atomics) -> per-bucket deg count -> per-bucket placement with 16-padding
// (dummy node N, isd[N]=0). agg kernels: scalarized node, unpredicated 16-deep MLP,
// isdn hoisted out of the edge loop. Intermediates bf16. GEMM1 = bf16 MFMA.

#define CHUNK   4096              // edges per partition block (392 blocks)
#define NPB     512               // nodes per bucket (dst >> 9)
#define NBUCK   196               // ceil(100000/512)
#define BBCAP   9216              // bucket capacity (mean 8163, +11 sigma)

typedef __bf16 bf16x8 __attribute__((ext_vector_type(8)));
typedef float floatx4 __attribute__((ext_vector_type(4)));

__device__ inline unsigned short f2bf(float f) {      // RNE fp32->bf16
    unsigned u = __float_as_uint(f);
    u += 0x7FFF + ((u >> 16) & 1);
    return (unsigned short)(u >> 16);
}
__device__ inline float bflo(unsigned p) { return __uint_as_float(p << 16); }
__device__ inline float bfhi(unsigned p) { return __uint_as_float(p & 0xFFFF0000u); }

// ---------------- pass 1: block-local radix partition by dst>>9 ----------------
// rec = src (17b) | (dst&511)<<17
__global__ __launch_bounds__(256) void k_part(const int* __restrict__ src,
                                              const int* __restrict__ dst,
                                              int* __restrict__ gcursor,
                                              unsigned* __restrict__ buckets, int E) {
    __shared__ unsigned srec[CHUNK];          // 16 KB
    __shared__ unsigned char sb8[CHUNK];      // 4 KB
    __shared__ int hist[NBUCK];
    __shared__ int lbase[NBUCK];
    __shared__ int gbase[NBUCK];
    __shared__ int scanbuf[256];
    int t = threadIdx.x;
    int base = blockIdx.x * CHUNK;
    int cnt = min(CHUNK, E - base);           // multiple of 4
    for (int i = t; i < NBUCK; i += 256) hist[i] = 0;
    __syncthreads();

    unsigned rec[16];
    unsigned br[16];                          // b (8b) | rank<<8
    bool valid[4];
    #pragma unroll
    for (int k = 0; k < 4; ++k) {
        int e0 = k * 1024 + t * 4;
        valid[k] = (e0 < cnt);
        if (valid[k]) {
            int4 s4 = *(const int4*)&src[base + e0];
            int4 d4 = *(const int4*)&dst[base + e0];
            int ss[4] = {s4.x, s4.y, s4.z, s4.w};
            int dd[4] = {d4.x, d4.y, d4.z, d4.w};
            #pragma unroll
            for (int j = 0; j < 4; ++j) {
                int b = dd[j] >> 9;
                int r = atomicAdd(&hist[b], 1);           // LDS atomic
                rec[k * 4 + j] = (unsigned)ss[j] | ((unsigned)(dd[j] & 511) << 17);
                br[k * 4 + j] = (unsigned)b | ((unsigned)r << 8);
            }
        }
    }
    __syncthreads();
    // inclusive Hillis-Steele scan over 256 (NBUCK padded)
    scanbuf[t] = (t < NBUCK) ? hist[t] : 0;
    __syncthreads();
    for (int s = 1; s < 256; s <<= 1) {
        int v = (t >= s) ? scanbuf[t - s] : 0;
        __syncthreads();
        scanbuf[t] += v;
        __syncthreads();
    }
    if (t < NBUCK) {
        lbase[t] = scanbuf[t] - hist[t];                  // exclusive base
        gbase[t] = atomicAdd(&gcursor[t], hist[t]);       // per-bucket global atomic
    }
    __syncthreads();
    // reorder into LDS, grouped by bucket
    #pragma unroll
    for (int k = 0; k < 4; ++k) {
        if (valid[k]) {
            #pragma unroll
            for (int j = 0; j < 4; ++j) {
                unsigned b = br[k * 4 + j] & 255u;
                unsigned r = br[k * 4 + j] >> 8;
                int p = lbase[b] + (int)r;
                srec[p] = rec[k * 4 + j];
                sb8[p] = (unsigned char)b;
            }
        }
    }
    __syncthreads();
    // dense flat write: consecutive i -> consecutive addresses within each run
    for (int i = t; i < cnt; i += 256) {
        int b = sb8[i];
        int pos = gbase[b] + (i - lbase[b]);
        if (pos < BBCAP) buckets[(size_t)b * BBCAP + pos] = srec[i];
    }
}

// ---------------- pass 2a: per-bucket deg histogram (dense) ----------------
__global__ __launch_bounds__(256) void k_count(const unsigned* __restrict__ buckets,
                                               const int* __restrict__ gcursor,
                                               int* __restrict__ deg, int N) {
    __shared__ int hist[NPB];
    int b = blockIdx.x;
    for (int i = threadIdx.x; i < NPB; i += 256) hist[i] = 0;
    __syncthreads();
    int cnt = min(gcursor[b], BBCAP);
    const unsigned* bk = &buckets[(size_t)b * BBCAP];
    for (int i = threadIdx.x; i < cnt; i += 256)
        atomicAdd(&hist[bk[i] >> 17], 1);
    __syncthreads();
    int node0 = b << 9;
    for (int i = threadIdx.x; i < NPB; i += 256)
        if (node0 + i < N) deg[node0 + i] = hist[i];
}

// ---------------- isd + offsets over PADDED degree (wave scan + 1 atomic/wave) -------
// isd has N+1 entries; isd[N]=0 (dummy). offsets has N+1 slots allocated.
__global__ void k_isd_offsets(const int* __restrict__ deg, float* __restrict__ isd,
                              int* __restrict__ offsets, int* __restrict__ counter, int N) {
    int n = blockIdx.x * blockDim.x + threadIdx.x;
    int lane = threadIdx.x & 63;
    int d = (n < N) ? deg[n] : 0;
    if (n <= N) isd[n] = (d > 0) ? rsqrtf((float)d) : 0.f;
    int dp = (d + 15) & ~15;                  // padded degree
    int pref = dp;
    #pragma unroll
    for (int sh = 1; sh < 64; sh <<= 1) {
        int t = __shfl_up(pref, sh);
        if (lane >= sh) pref += t;
    }
    int total = __shfl(pref, 63);
    int base = 0;
    if (lane == 63) base = atomicAdd(counter, total);
    base = __shfl(base, 63);
    if (n < N) offsets[n] = base + pref - dp;
}

// ---------------- pass 2b: placement via LDS cursors + dummy-pad fill ----------------
__global__ __launch_bounds__(256) void k_place(const unsigned* __restrict__ buckets,
                                               const int* __restrict__ gcursor,
                                               const int* __restrict__ offsets,
                                               const int* __restrict__ deg,
                                               int* __restrict__ csr, int N) {
    __shared__ int cur[NPB];
    int b = blockIdx.x;
    int node0 = b << 9;
    for (int i = threadIdx.x; i < NPB; i += 256)
        cur[i] = (node0 + i < N) ? offsets[node0 + i] : 0;
    __syncthreads();
    int cnt = min(gcursor[b], BBCAP);
    const unsigned* bk = &buckets[(size_t)b * BBCAP];
    for (int i = threadIdx.x; i < cnt; i += 256) {
        unsigned r = bk[i];
        int p = atomicAdd(&cur[r >> 17], 1);
        csr[p] = (int)(r & 0x1FFFFu);
    }
    __syncthreads();
    // fill pad region [offset+deg, offset+paddeg) with dummy node N (isd[N]=0)
    for (int i = threadIdx.x; i < NPB; i += 256) {
        int n = node0 + i;
        if (n < N) {
            int d = deg[n];
            int st = offsets[n] + d;
            int en = offsets[n] + ((d + 15) & ~15);
            for (int p = st; p < en; ++p) csr[p] = N;
        }
    }
}

// ---------------- W1 -> bf16, MFMA B-fragment order ----------------
__global__ void k_prep_w1(const float* __restrict__ W1, unsigned short* __restrict__ w1s) {
    int flat = blockIdx.x * 256 + threadIdx.x;   // 0..4095
    int kt = flat >> 9;
    int nt = (flat >> 6) & 7;
    int lane = flat & 63;
    int kbase = kt * 32 + ((lane >> 4) << 3);
    int n = nt * 16 + (lane & 15);
    unsigned short v[8];
    #pragma unroll
    for (int j = 0; j < 8; ++j) v[j] = f2bf(W1[(size_t)(kbase + j) * 128 + n]);
    unsigned short* d = &w1s[(size_t)flat * 8];
    *(short4*)(d)     = make_short4(v[0], v[1], v[2], v[3]);
    *(short4*)(d + 4) = make_short4(v[4], v[5], v[6], v[7]);
}

// ---------------- GEMM1: h[N,128](bf16) = x[N,256] @ W1 , MFMA 16x16x32 ----------------
__global__ __launch_bounds__(256) void k_gemm1(const float* __restrict__ X,
                                               const unsigned short* __restrict__ w1s,
                                               unsigned short* __restrict__ H, int N) {
    __shared__ __align__(16) unsigned short smem[8192];
    unsigned short* sA = smem;
    unsigned short* sB = smem + 2048;
    int tid = threadIdx.x;
    int lane = tid & 63;
    int wave = tid >> 6;
    int wr = wave >> 1;
    int wc = wave & 1;
    int m0 = blockIdx.x * 64;

    floatx4 acc[2][4] = {};

    for (int kt = 0; kt < 8; ++kt) {
        #pragma unroll
        for (int i = 0; i < 2; ++i) {
            int f = tid * 2 + i;
            int row = f >> 3;
            int c4 = (f & 7) * 4;
            float4 v = make_float4(0.f, 0.f, 0.f, 0.f);
            int grow = m0 + row;
            if (grow < N) v = *(const float4*)&X[(size_t)grow * 256 + kt * 32 + c4];
            int mt = row >> 4;
            int flane = (row & 15) | ((c4 >> 3) << 4);
            int j0 = c4 & 7;
            unsigned short* d = &sA[(size_t)(mt * 64 + flane) * 8 + j0];
            *(short4*)d = make_short4(f2bf(v.x), f2bf(v.y), f2bf(v.z), f2bf(v.w));
        }
        {
            const float4* srcp = (const float4*)&w1s[(size_t)kt * 4096];
            float4* dstp = (float4*)sB;
            dstp[tid] = srcp[tid];
            dstp[tid + 256] = srcp[tid + 256];
        }
        __syncthreads();
        bf16x8 a[2], b[4];
        #pragma unroll
        for (int p = 0; p < 2; ++p)
            a[p] = *(const bf16x8*)&sA[(size_t)((wr * 2 + p) * 64 + lane) * 8];
        #pragma unroll
        for (int q = 0; q < 4; ++q)
            b[q] = *(const bf16x8*)&sB[(size_t)((wc * 4 + q) * 64 + lane) * 8];
        #pragma unroll
        for (int p = 0; p < 2; ++p)
            #pragma unroll
            for (int q = 0; q < 4; ++q)
                acc[p][q] = __builtin_amdgcn_mfma_f32_16x16x32_bf16(a[p], b[q], acc[p][q], 0, 0, 0);
        __syncthreads();
    }
    #pragma unroll
    for (int p = 0; p < 2; ++p)
        #pragma unroll
        for (int q = 0; q < 4; ++q)
            #pragma unroll
            for (int r = 0; r < 4; ++r) {
                int rl = wr * 32 + p * 16 + ((lane >> 4) << 2) + r;
                int c = wc * 64 + q * 16 + (lane & 15);
                smem[rl * 128 + c] = f2bf(acc[p][q][r]);
            }
    __syncthreads();
    #pragma unroll
    for (int i = 0; i < 4; ++i) {
        int f = tid + i * 256;
        int row = f >> 4;
        int c8 = (f & 15) * 8;
        int grow = m0 + row;
        if (grow < N)
            *(float4*)&H[(size_t)grow * 128 + c8] = *(const float4*)&smem[row * 128 + c8];
    }
}

// ---------------- agg1: h1(bf16) = relu(b1 + isdn * sum isd[s]*h[src]) , C=128 -------
// wave/node; scalar node; padded csr => no predication; 16 gathers in flight
__global__ __launch_bounds__(256) void k_agg1(const unsigned* __restrict__ Hu,
                                              const int* __restrict__ csr,
                                              const float* __restrict__ isd,
                                              const int* __restrict__ offsets,
                                              const int* __restrict__ deg,
                                              const float* __restrict__ b1,
                                              unsigned* __restrict__ H1u, int N) {
    int node = __builtin_amdgcn_readfirstlane((blockIdx.x * blockDim.x + threadIdx.x) >> 6);
    int lane = threadIdx.x & 63;
    if (node >= N) return;
    int start = offsets[node];
    int nb = (deg[node] + 15) >> 4;
    float isdn = isd[node];
    float acc0 = 0.f, acc1 = 0.f;
    for (int ib = 0; ib < nb; ++ib) {
        int b0 = start + ib * 16;
        int s[16];
        float f[16];
        #pragma unroll
        for (int j = 0; j < 16; ++j) {
            s[j] = csr[b0 + j];               // scalar (wave-uniform addr)
            f[j] = isd[s[j]];                 // scalar; 0 for dummy
        }
        unsigned p[16];
        #pragma unroll
        for (int j = 0; j < 16; ++j) p[j] = Hu[(size_t)s[j] * 64 + lane];
        #pragma unroll
        for (int j = 0; j < 16; ++j) {
            acc0 = fmaf(f[j], bflo(p[j]), acc0);
            acc1 = fmaf(f[j], bfhi(p[j]), acc1);
        }
    }
    float r0 = fmaxf(fmaf(isdn, acc0, b1[2 * lane]), 0.f);
    float r1 = fmaxf(fmaf(isdn, acc1, b1[2 * lane + 1]), 0.f);
    H1u[(size_t)node * 64 + lane] = (unsigned)f2bf(r0) | ((unsigned)f2bf(r1) << 16);
}

// ---------------- GEMM2: h2[N,40](bf16) = h1(bf16) @ W2[128,40] ----------------
__global__ __launch_bounds__(256) void k_gemm2(const unsigned short* __restrict__ H1,
                                               const float* __restrict__ W2,
                                               unsigned short* __restrict__ H2, int N) {
    __shared__ float sH[64][132];
    __shared__ float sW[128 * 40];
    int tid = threadIdx.x;
    int block_row = blockIdx.x * 64;
    for (int i = tid; i < 64 * 16; i += 256) {
        int r = i >> 4;
        int c8 = (i & 15) * 8;
        int grow = block_row + r;
        uint4 v = make_uint4(0, 0, 0, 0);
        if (grow < N) v = *(const uint4*)&H1[(size_t)grow * 128 + c8];
        float* d = &sH[r][c8];
        d[0] = bflo(v.x); d[1] = bfhi(v.x);
        d[2] = bflo(v.y); d[3] = bfhi(v.y);
        d[4] = bflo(v.z); d[5] = bfhi(v.z);
        d[6] = bflo(v.w); d[7] = bfhi(v.w);
    }
    for (int i = tid; i < 1280; i += 256)
        *(float4*)&sW[i * 4] = *(const float4*)&W2[(size_t)i * 4];
    __syncthreads();

    int row = tid >> 2;
    int c0 = (tid & 3) * 10;
    float acc[10] = {};
    for (int k = 0; k < 128; ++k) {
        float hv = sH[row][k];
        #pragma unroll
        for (int j = 0; j < 5; ++j) {
            float2 wv = *(const float2*)&sW[k * 40 + c0 + 2 * j];
            acc[2 * j]     = fmaf(hv, wv.x, acc[2 * j]);
            acc[2 * j + 1] = fmaf(hv, wv.y, acc[2 * j + 1]);
        }
    }
    int grow = block_row + row;
    if (grow < N) {
        unsigned* o = (unsigned*)&H2[(size_t)grow * 40 + c0];
        #pragma unroll
        for (int j = 0; j < 5; ++j)
            o[j] = (unsigned)f2bf(acc[2 * j]) | ((unsigned)f2bf(acc[2 * j + 1]) << 16);
    }
}

// ---------------- agg2: out = b2 + isdn * sum isd[s]*h2[src] , C=40 ----------------
// lane = 20*g + c : 3 edge-groups in parallel; real entries only (pads skipped)
__global__ __launch_bounds__(256) void k_agg2(const unsigned* __restrict__ Hu,
                                              const int* __restrict__ csr,
                                              const float* __restrict__ isd,
                                              const int* __restrict__ offsets,
                                              const int* __restrict__ deg,
                                              const float* __restrict__ b2,
                                              float* __restrict__ out, int N) {
    int node = __builtin_amdgcn_readfirstlane((blockIdx.x * blockDim.x + threadIdx.x) >> 6);
    int lane = threadIdx.x & 63;
    if (node >= N) return;
    int start = offsets[node];
    int cnt = deg[node];
    float isdn = isd[node];
    int g = lane / 20;         // 0..3 (g==3 idle)
    int c = lane % 20;
    bool active = g < 3;
    float acc0 = 0.f, acc1 = 0.f;
    for (int i0 = 0; i0 < cnt; i0 += 12) {
        #pragma unroll
        for (int j = 0; j < 4; ++j) {
            int e = i0 + j * 3 + g;
            if (active && e < cnt) {
                int s = csr[start + e];
                unsigned p = Hu[(size_t)s * 20 + c];
                float w = isd[s];
                acc0 = fmaf(w, bflo(p), acc0);
                acc1 = fmaf(w, bfhi(p), acc1);
            }
        }
    }
    float t0 = __shfl(acc0, (lane + 20) & 63) + __shfl(acc0, (lane + 40) & 63);
    float t1 = __shfl(acc1, (lane + 20) & 63) + __shfl(acc1, (lane + 40) & 63);
    acc0 += t0;
    acc1 += t1;
    if (lane < 20)
        *(float2*)&out[(size_t)node * 40 + 2 * lane] =
            make_float2(fmaf(isdn, acc0, b2[2 * lane]), fmaf(isdn, acc1, b2[2 * lane + 1]));
}

extern "C" void kernel_launch(void* const* d_in, const int* in_sizes, int n_in,
                              void* d_out, int out_size, void* d_ws, size_t ws_size,
                              hipStream_t stream) {
    const float* x  = (const float*)d_in[0];
    const int*  src = (const int*)d_in[1];
    const int*  dst = (const int*)d_in[2];
    const float* W1 = (const float*)d_in[3];
    const float* b1 = (const float*)d_in[4];
    const float* W2 = (const float*)d_in[5];
    const float* b2 = (const float*)d_in[6];
    float* out = (float*)d_out;

    const int N = in_sizes[0] / 256;   // 100000
    const int E = in_sizes[1];         // 1600000

    char* w = (char*)d_ws;
    auto alloc = [&](size_t bytes) -> void* {
        void* p = (void*)w;
        w += (bytes + 15) & ~(size_t)15;
        return p;
    };
    int*      gcursor = (int*)alloc(256 * 4);                 // zeroed (NBUCK used)
    int*      counter = (int*)alloc(16);                      // zeroed
    int*      deg     = (int*)alloc((size_t)N * 4);           // fully written by k_count
    float*    isd     = (float*)alloc((size_t)(N + 1) * 4);
    int*      offsets = (int*)alloc((size_t)(N + 1) * 4);
    unsigned* buckets = (unsigned*)alloc((size_t)NBUCK * BBCAP * 4);
    int*      csr     = (int*)alloc((size_t)(E + 16 * (size_t)N) * 4);  // padded
    unsigned short* w1s = (unsigned short*)alloc(32768 * 2);
    unsigned short* h   = (unsigned short*)alloc((size_t)(N + 1) * 128 * 2);  // +dummy row
    unsigned short* h1  = (unsigned short*)alloc((size_t)N * 128 * 2);
    unsigned short* h2  = h;   // h dead after agg1

    hipMemsetAsync(gcursor, 0, 256 * 4 + 16, stream);

    int nchunk = (E + CHUNK - 1) / CHUNK;   // 392
    k_part<<<nchunk, 256, 0, stream>>>(src, dst, gcursor, buckets, E);
    k_count<<<NBUCK, 256, 0, stream>>>(buckets, gcursor, deg, N);
    k_isd_offsets<<<(N + 256) / 256, 256, 0, stream>>>(deg, isd, offsets, counter, N);
    k_place<<<NBUCK, 256, 0, stream>>>(buckets, gcursor, offsets, deg, csr, N);
    k_prep_w1<<<16, 256, 0, stream>>>(W1, w1s);
    k_gemm1<<<(N + 63) / 64, 256, 0, stream>>>(x, w1s, h, N);
    k_agg1<<<(N + 3) / 4, 256, 0, stream>>>((const unsigned*)h, csr, isd, offsets, deg,
                                            b1, (unsigned*)h1, N);
    k_gemm2<<<(N + 63) / 64, 256, 0, stream>>>(h1, W2, h2, N);
    k_agg2<<<(N + 3) / 4, 256, 0, stream>>>((const unsigned*)h2, csr, isd, offsets, deg,
                                            b2, out, N);
}

// Round 7
// 409.935 us; speedup vs baseline: 2.0860x; 1.0798x over previous
//
#include <hip/hip_runtime.h>
#include <hip/hip_bf16.h>

// GCN 2-layer. CSR via block-local radix partition, 16-padded lists (dummy node N).
// h' = isd*(x@W1) and h2' = isd*(h1@W2) pre-scaled at the producer => agg loops are
// pure {index load, row gather, unpack, add}. Intermediates bf16. GEMM1 = bf16 MFMA.

#define CHUNK   4096              // edges per partition block (392 blocks)
#define NPB     512               // nodes per bucket (dst >> 9)
#define NBUCK   196               // ceil(100000/512)
#define BBCAP   9216              // bucket capacity (mean 8163, +11 sigma)

typedef __bf16 bf16x8 __attribute__((ext_vector_type(8)));
typedef float floatx4 __attribute__((ext_vector_type(4)));

__device__ inline unsigned short f2bf(float f) {      // RNE fp32->bf16
    unsigned u = __float_as_uint(f);
    u += 0x7FFF + ((u >> 16) & 1);
    return (unsigned short)(u >> 16);
}
__device__ inline float bflo(unsigned p) { return __uint_as_float(p << 16); }
__device__ inline float bfhi(unsigned p) { return __uint_as_float(p & 0xFFFF0000u); }

// ---------------- pass 1: block-local radix partition by dst>>9 ----------------
// rec = src (17b) | (dst&511)<<17
__global__ __launch_bounds__(256) void k_part(const int* __restrict__ src,
                                              const int* __restrict__ dst,
                                              int* __restrict__ gcursor,
                                              unsigned* __restrict__ buckets, int E) {
    __shared__ unsigned srec[CHUNK];          // 16 KB
    __shared__ unsigned char sb8[CHUNK];      // 4 KB
    __shared__ int hist[NBUCK];
    __shared__ int lbase[NBUCK];
    __shared__ int gbase[NBUCK];
    __shared__ int scanbuf[256];
    int t = threadIdx.x;
    int base = blockIdx.x * CHUNK;
    int cnt = min(CHUNK, E - base);           // multiple of 4
    for (int i = t; i < NBUCK; i += 256) hist[i] = 0;
    __syncthreads();

    unsigned rec[16];
    unsigned br[16];                          // b (8b) | rank<<8
    bool valid[4];
    #pragma unroll
    for (int k = 0; k < 4; ++k) {
        int e0 = k * 1024 + t * 4;
        valid[k] = (e0 < cnt);
        if (valid[k]) {
            int4 s4 = *(const int4*)&src[base + e0];
            int4 d4 = *(const int4*)&dst[base + e0];
            int ss[4] = {s4.x, s4.y, s4.z, s4.w};
            int dd[4] = {d4.x, d4.y, d4.z, d4.w};
            #pragma unroll
            for (int j = 0; j < 4; ++j) {
                int b = dd[j] >> 9;
                int r = atomicAdd(&hist[b], 1);           // LDS atomic
                rec[k * 4 + j] = (unsigned)ss[j] | ((unsigned)(dd[j] & 511) << 17);
                br[k * 4 + j] = (unsigned)b | ((unsigned)r << 8);
            }
        }
    }
    __syncthreads();
    // inclusive Hillis-Steele scan over 256 (NBUCK padded)
    scanbuf[t] = (t < NBUCK) ? hist[t] : 0;
    __syncthreads();
    for (int s = 1; s < 256; s <<= 1) {
        int v = (t >= s) ? scanbuf[t - s] : 0;
        __syncthreads();
        scanbuf[t] += v;
        __syncthreads();
    }
    if (t < NBUCK) {
        lbase[t] = scanbuf[t] - hist[t];                  // exclusive base
        gbase[t] = atomicAdd(&gcursor[t], hist[t]);       // per-bucket global atomic
    }
    __syncthreads();
    // reorder into LDS, grouped by bucket
    #pragma unroll
    for (int k = 0; k < 4; ++k) {
        if (valid[k]) {
            #pragma unroll
            for (int j = 0; j < 4; ++j) {
                unsigned b = br[k * 4 + j] & 255u;
                unsigned r = br[k * 4 + j] >> 8;
                int p = lbase[b] + (int)r;
                srec[p] = rec[k * 4 + j];
                sb8[p] = (unsigned char)b;
            }
        }
    }
    __syncthreads();
    // dense flat write
    for (int i = t; i < cnt; i += 256) {
        int b = sb8[i];
        int pos = gbase[b] + (i - lbase[b]);
        if (pos < BBCAP) buckets[(size_t)b * BBCAP + pos] = srec[i];
    }
}

// ---------------- pass 2a: per-bucket deg histogram (dense) ----------------
__global__ __launch_bounds__(256) void k_count(const unsigned* __restrict__ buckets,
                                               const int* __restrict__ gcursor,
                                               int* __restrict__ deg, int N) {
    __shared__ int hist[NPB];
    int b = blockIdx.x;
    for (int i = threadIdx.x; i < NPB; i += 256) hist[i] = 0;
    __syncthreads();
    int cnt = min(gcursor[b], BBCAP);
    const unsigned* bk = &buckets[(size_t)b * BBCAP];
    for (int i = threadIdx.x; i < cnt; i += 256)
        atomicAdd(&hist[bk[i] >> 17], 1);
    __syncthreads();
    int node0 = b << 9;
    for (int i = threadIdx.x; i < NPB; i += 256)
        if (node0 + i < N) deg[node0 + i] = hist[i];
}

// ---------------- isd + offsets over PADDED degree ----------------
__global__ void k_isd_offsets(const int* __restrict__ deg, float* __restrict__ isd,
                              int* __restrict__ offsets, int* __restrict__ counter, int N) {
    int n = blockIdx.x * blockDim.x + threadIdx.x;
    int lane = threadIdx.x & 63;
    int d = (n < N) ? deg[n] : 0;
    if (n <= N) isd[n] = (d > 0) ? rsqrtf((float)d) : 0.f;   // isd[N]=0 dummy
    int dp = (d + 15) & ~15;                  // padded degree
    int pref = dp;
    #pragma unroll
    for (int sh = 1; sh < 64; sh <<= 1) {
        int t = __shfl_up(pref, sh);
        if (lane >= sh) pref += t;
    }
    int total = __shfl(pref, 63);
    int base = 0;
    if (lane == 63) base = atomicAdd(counter, total);
    base = __shfl(base, 63);
    if (n < N) offsets[n] = base + pref - dp;
}

// ---------------- pass 2b: placement via LDS cursors + dummy-pad fill ----------------
__global__ __launch_bounds__(256) void k_place(const unsigned* __restrict__ buckets,
                                               const int* __restrict__ gcursor,
                                               const int* __restrict__ offsets,
                                               const int* __restrict__ deg,
                                               int* __restrict__ csr, int N) {
    __shared__ int cur[NPB];
    int b = blockIdx.x;
    int node0 = b << 9;
    for (int i = threadIdx.x; i < NPB; i += 256)
        cur[i] = (node0 + i < N) ? offsets[node0 + i] : 0;
    __syncthreads();
    int cnt = min(gcursor[b], BBCAP);
    const unsigned* bk = &buckets[(size_t)b * BBCAP];
    for (int i = threadIdx.x; i < cnt; i += 256) {
        unsigned r = bk[i];
        int p = atomicAdd(&cur[r >> 17], 1);
        csr[p] = (int)(r & 0x1FFFFu);
    }
    __syncthreads();
    // fill pad region with dummy node N (h'[N] = 0, h2'[N] = 0)
    for (int i = threadIdx.x; i < NPB; i += 256) {
        int n = node0 + i;
        if (n < N) {
            int d = deg[n];
            int st = offsets[n] + d;
            int en = offsets[n] + ((d + 15) & ~15);
            for (int p = st; p < en; ++p) csr[p] = N;
        }
    }
}

// ---------------- W1 -> bf16 MFMA B-fragment order; zero h2' dummy row ----------------
__global__ void k_prep_w1(const float* __restrict__ W1, unsigned short* __restrict__ w1s,
                          unsigned* __restrict__ h2z) {
    if (blockIdx.x == 0 && threadIdx.x < 36) h2z[threadIdx.x] = 0;  // row N + slack
    int flat = blockIdx.x * 256 + threadIdx.x;   // 0..4095
    int kt = flat >> 9;
    int nt = (flat >> 6) & 7;
    int lane = flat & 63;
    int kbase = kt * 32 + ((lane >> 4) << 3);
    int n = nt * 16 + (lane & 15);
    unsigned short v[8];
    #pragma unroll
    for (int j = 0; j < 8; ++j) v[j] = f2bf(W1[(size_t)(kbase + j) * 128 + n]);
    unsigned short* d = &w1s[(size_t)flat * 8];
    *(short4*)(d)     = make_short4(v[0], v[1], v[2], v[3]);
    *(short4*)(d + 4) = make_short4(v[4], v[5], v[6], v[7]);
}

// ---------------- GEMM1: h'[N+1,128](bf16) = isd*(x @ W1) , MFMA 16x16x32 ----------------
__global__ __launch_bounds__(256) void k_gemm1(const float* __restrict__ X,
                                               const unsigned short* __restrict__ w1s,
                                               const float* __restrict__ isd,
                                               unsigned short* __restrict__ H, int N) {
    __shared__ __align__(16) unsigned short smem[8192];
    unsigned short* sA = smem;
    unsigned short* sB = smem + 2048;
    int tid = threadIdx.x;
    int lane = tid & 63;
    int wave = tid >> 6;
    int wr = wave >> 1;
    int wc = wave & 1;
    int m0 = blockIdx.x * 64;

    floatx4 acc[2][4] = {};

    for (int kt = 0; kt < 8; ++kt) {
        #pragma unroll
        for (int i = 0; i < 2; ++i) {
            int f = tid * 2 + i;
            int row = f >> 3;
            int c4 = (f & 7) * 4;
            float4 v = make_float4(0.f, 0.f, 0.f, 0.f);
            int grow = m0 + row;
            if (grow < N) v = *(const float4*)&X[(size_t)grow * 256 + kt * 32 + c4];
            int mt = row >> 4;
            int flane = (row & 15) | ((c4 >> 3) << 4);
            int j0 = c4 & 7;
            unsigned short* d = &sA[(size_t)(mt * 64 + flane) * 8 + j0];
            *(short4*)d = make_short4(f2bf(v.x), f2bf(v.y), f2bf(v.z), f2bf(v.w));
        }
        {
            const float4* srcp = (const float4*)&w1s[(size_t)kt * 4096];
            float4* dstp = (float4*)sB;
            dstp[tid] = srcp[tid];
            dstp[tid + 256] = srcp[tid + 256];
        }
        __syncthreads();
        bf16x8 a[2], b[4];
        #pragma unroll
        for (int p = 0; p < 2; ++p)
            a[p] = *(const bf16x8*)&sA[(size_t)((wr * 2 + p) * 64 + lane) * 8];
        #pragma unroll
        for (int q = 0; q < 4; ++q)
            b[q] = *(const bf16x8*)&sB[(size_t)((wc * 4 + q) * 64 + lane) * 8];
        #pragma unroll
        for (int p = 0; p < 2; ++p)
            #pragma unroll
            for (int q = 0; q < 4; ++q)
                acc[p][q] = __builtin_amdgcn_mfma_f32_16x16x32_bf16(a[p], b[q], acc[p][q], 0, 0, 0);
        __syncthreads();
    }
    // per-row isd scale factors (8 rows per thread)
    float sc[2][4];
    #pragma unroll
    for (int p = 0; p < 2; ++p)
        #pragma unroll
        for (int r = 0; r < 4; ++r) {
            int g = m0 + wr * 32 + p * 16 + ((lane >> 4) << 2) + r;
            sc[p][r] = isd[g > N ? N : g];
        }
    #pragma unroll
    for (int p = 0; p < 2; ++p)
        #pragma unroll
        for (int q = 0; q < 4; ++q)
            #pragma unroll
            for (int r = 0; r < 4; ++r) {
                int rl = wr * 32 + p * 16 + ((lane >> 4) << 2) + r;
                int c = wc * 64 + q * 16 + (lane & 15);
                smem[rl * 128 + c] = f2bf(acc[p][q][r] * sc[p][r]);
            }
    __syncthreads();
    #pragma unroll
    for (int i = 0; i < 4; ++i) {
        int f = tid + i * 256;
        int row = f >> 4;
        int c8 = (f & 15) * 8;
        int grow = m0 + row;
        if (grow <= N)   // row N = zeros (dummy)
            *(float4*)&H[(size_t)grow * 128 + c8] = *(const float4*)&smem[row * 128 + c8];
    }
}

// ---------------- agg1: h1(bf16) = relu(b1 + isdn * sum h'[src]) , C=128 ----------------
__global__ __launch_bounds__(256) void k_agg1(const unsigned* __restrict__ Hu,
                                              const int* __restrict__ csr,
                                              const float* __restrict__ isd,
                                              const int* __restrict__ offsets,
                                              const int* __restrict__ deg,
                                              const float* __restrict__ b1,
                                              unsigned* __restrict__ H1u, int N) {
    int node = __builtin_amdgcn_readfirstlane((blockIdx.x * blockDim.x + threadIdx.x) >> 6);
    int lane = threadIdx.x & 63;
    if (node >= N) return;
    int start = offsets[node];
    int nb = (deg[node] + 15) >> 4;
    float isdn = isd[node];
    float acc0 = 0.f, acc1 = 0.f;
    for (int ib = 0; ib < nb; ++ib) {
        int b0 = start + ib * 16;
        int s[16];
        #pragma unroll
        for (int j = 0; j < 16; ++j) s[j] = csr[b0 + j];        // scalar loads
        unsigned p[16];
        #pragma unroll
        for (int j = 0; j < 16; ++j) p[j] = Hu[(size_t)s[j] * 64 + lane];
        #pragma unroll
        for (int j = 0; j < 16; ++j) {
            acc0 += bflo(p[j]);
            acc1 += bfhi(p[j]);
        }
    }
    float r0 = fmaxf(fmaf(isdn, acc0, b1[2 * lane]), 0.f);
    float r1 = fmaxf(fmaf(isdn, acc1, b1[2 * lane + 1]), 0.f);
    H1u[(size_t)node * 64 + lane] = (unsigned)f2bf(r0) | ((unsigned)f2bf(r1) << 16);
}

// ---------------- GEMM2: h2'[N+1,40](bf16) = isd*(h1 @ W2) ----------------
__global__ __launch_bounds__(256) void k_gemm2(const unsigned short* __restrict__ H1,
                                               const float* __restrict__ W2,
                                               const float* __restrict__ isd,
                                               unsigned short* __restrict__ H2, int N) {
    __shared__ float sH[64][132];
    __shared__ float sW[128 * 40];
    int tid = threadIdx.x;
    int block_row = blockIdx.x * 64;
    for (int i = tid; i < 64 * 16; i += 256) {
        int r = i >> 4;
        int c8 = (i & 15) * 8;
        int grow = block_row + r;
        uint4 v = make_uint4(0, 0, 0, 0);
        if (grow < N) v = *(const uint4*)&H1[(size_t)grow * 128 + c8];
        float* d = &sH[r][c8];
        d[0] = bflo(v.x); d[1] = bfhi(v.x);
        d[2] = bflo(v.y); d[3] = bfhi(v.y);
        d[4] = bflo(v.z); d[5] = bfhi(v.z);
        d[6] = bflo(v.w); d[7] = bfhi(v.w);
    }
    for (int i = tid; i < 1280; i += 256)
        *(float4*)&sW[i * 4] = *(const float4*)&W2[(size_t)i * 4];
    __syncthreads();

    int row = tid >> 2;
    int c0 = (tid & 3) * 10;
    float acc[10] = {};
    for (int k = 0; k < 128; ++k) {
        float hv = sH[row][k];
        #pragma unroll
        for (int j = 0; j < 5; ++j) {
            float2 wv = *(const float2*)&sW[k * 40 + c0 + 2 * j];
            acc[2 * j]     = fmaf(hv, wv.x, acc[2 * j]);
            acc[2 * j + 1] = fmaf(hv, wv.y, acc[2 * j + 1]);
        }
    }
    int grow = block_row + row;
    if (grow < N) {
        float scn = isd[grow];
        unsigned* o = (unsigned*)&H2[(size_t)grow * 40 + c0];
        #pragma unroll
        for (int j = 0; j < 5; ++j)
            o[j] = (unsigned)f2bf(acc[2 * j] * scn) |
                   ((unsigned)f2bf(acc[2 * j + 1] * scn) << 16);
    }
}

// ---------------- agg2: out = b2 + isdn * sum h2'[src] , C=40 ----------------
// sub = lane>>5 (2 edges/instr), c = lane&31 (c<20 active); 8-deep MLP, unpredicated
__global__ __launch_bounds__(256) void k_agg2(const unsigned* __restrict__ Hu2,
                                              const int* __restrict__ csr,
                                              const float* __restrict__ isd,
                                              const int* __restrict__ offsets,
                                              const int* __restrict__ deg,
                                              const float* __restrict__ b2,
                                              float* __restrict__ out, int N) {
    int node = __builtin_amdgcn_readfirstlane((blockIdx.x * blockDim.x + threadIdx.x) >> 6);
    int lane = threadIdx.x & 63;
    if (node >= N) return;
    int start = offsets[node];
    int nb = (deg[node] + 15) >> 4;
    float isdn = isd[node];
    int sub = lane >> 5;       // 0/1
    int c = lane & 31;         // active c<20; c in [20,32) reads slack (finite, unused)
    float acc0 = 0.f, acc1 = 0.f;
    for (int ib = 0; ib < nb; ++ib) {
        int b0 = start + ib * 16;
        #pragma unroll
        for (int j = 0; j < 8; ++j) {
            int s = csr[b0 + (j << 1) + sub];
            unsigned q = Hu2[(size_t)s * 20 + c];
            acc0 += bflo(q);
            acc1 += bfhi(q);
        }
    }
    acc0 += __shfl(acc0, lane + 32);
    acc1 += __shfl(acc1, lane + 32);
    if (lane < 20)
        *(float2*)&out[(size_t)node * 40 + 2 * lane] =
            make_float2(fmaf(isdn, acc0, b2[2 * lane]), fmaf(isdn, acc1, b2[2 * lane + 1]));
}

extern "C" void kernel_launch(void* const* d_in, const int* in_sizes, int n_in,
                              void* d_out, int out_size, void* d_ws, size_t ws_size,
                              hipStream_t stream) {
    const float* x  = (const float*)d_in[0];
    const int*  src = (const int*)d_in[1];
    const int*  dst = (const int*)d_in[2];
    const float* W1 = (const float*)d_in[3];
    const float* b1 = (const float*)d_in[4];
    const float* W2 = (const float*)d_in[5];
    const float* b2 = (const float*)d_in[6];
    float* out = (float*)d_out;

    const int N = in_sizes[0] / 256;   // 100000
    const int E = in_sizes[1];         // 1600000

    char* w = (char*)d_ws;
    auto alloc = [&](size_t bytes) -> void* {
        void* p = (void*)w;
        w += (bytes + 15) & ~(size_t)15;
        return p;
    };
    int*      gcursor = (int*)alloc(256 * 4);                 // zeroed
    int*      counter = (int*)alloc(16);                      // zeroed
    int*      deg     = (int*)alloc((size_t)N * 4);
    float*    isd     = (float*)alloc((size_t)(N + 1) * 4);
    int*      offsets = (int*)alloc((size_t)(N + 1) * 4);
    unsigned* buckets = (unsigned*)alloc((size_t)NBUCK * BBCAP * 4);
    int*      csr     = (int*)alloc((size_t)(E + 16 * (size_t)N) * 4);
    unsigned short* w1s = (unsigned short*)alloc(32768 * 2);
    unsigned short* h   = (unsigned short*)alloc((size_t)(N + 1) * 128 * 2);  // h'
    unsigned short* h1  = (unsigned short*)alloc((size_t)N * 128 * 2);
    unsigned short* h2  = (unsigned short*)alloc(((size_t)(N + 1) * 20 + 16) * 4);  // h2'

    hipMemsetAsync(gcursor, 0, 256 * 4 + 16, stream);

    int nchunk = (E + CHUNK - 1) / CHUNK;   // 392
    k_part<<<nchunk, 256, 0, stream>>>(src, dst, gcursor, buckets, E);
    k_count<<<NBUCK, 256, 0, stream>>>(buckets, gcursor, deg, N);
    k_isd_offsets<<<(N + 256) / 256, 256, 0, stream>>>(deg, isd, offsets, counter, N);
    k_place<<<NBUCK, 256, 0, stream>>>(buckets, gcursor, offsets, deg, csr, N);
    k_prep_w1<<<16, 256, 0, stream>>>(W1, w1s, (unsigned*)h2 + (size_t)N * 20);
    k_gemm1<<<(N + 63) / 64, 256, 0, stream>>>(x, w1s, isd, h, N);
    k_agg1<<<(N + 3) / 4, 256, 0, stream>>>((const unsigned*)h, csr, isd, offsets, deg,
                                            b1, (unsigned*)h1, N);
    k_gemm2<<<(N + 63) / 64, 256, 0, stream>>>(h1, W2, isd, h2, N);
    k_agg2<<<(N + 3) / 4, 256, 0, stream>>>((const unsigned*)h2, csr, isd, offsets, deg,
                                            b2, out, N);
}